// Round 9
// baseline (326.946 us; speedup 1.0000x reference)
//
#include <hip/hip_runtime.h>
#include <hip/hip_fp16.h>

// 3-layer gather-GEMM GNN (N=262144, K=8, 16->128->128->16), f16 MFMA.
// Round 21: halve layer1p's LDS-read traffic — the real binder. Arithmetic:
// r19 issued one fresh 1KB ds_read_b128 A-fragment PER MFMA (144 LDS
// wave-instrs/nb/block); at ~85 B/cy/CU LDS throughput that alone is ~90us
// across the grid = the frozen 117us floor (r20's deeper gather pipeline
// REGRESSED -> latency cover was never the binder; reverted to depth-2).
// Fix: remap 8 waves as (wm = w>>2: row half) x (wt = w&3: col pair); each
// wave computes 2 row-tiles x 2 col-tiles, so each A-read feeds 2 MFMAs:
// 8 reads -> 16 MFMAs per wave per nb. Block LDS traffic 144 -> 80 KB/nb.
// Same MFMA count, same staging, same barriers; every acc element
// accumulates over (nb, ks) in the same order -> bit-identical output.
// Regs ~90 < 128 at (512,4), spill-free. P-phase gets the same mapping.
// prep_all / layer0 / reduce unchanged.
//
// Workspace: ws = h1 (64 MiB) + P (64 MiB) = 128 MiB exactly. invd/h16/Wf live
// in d_out scratch; invd is d2d-copied into dead h1 before the reduce (which
// writes d_out).

typedef _Float16 f16x8 __attribute__((ext_vector_type(8)));
typedef float f32x4 __attribute__((ext_vector_type(4)));

#define NNODES 262144

// ---- Fused prep: [0,16384) conv_h | [16384,24576) prep_edges |
//      [24576,24640) shuffle W0 | [24640,25152) shuffle W1 |
//      [25152,25216) shuffle W2s ----
__global__ __launch_bounds__(256) void prep_all_kernel(
    const float* __restrict__ h, __half* __restrict__ h16,
    const float* __restrict__ pos, const int* __restrict__ nbr,
    __half* __restrict__ invd,
    const float* __restrict__ W0, __half* __restrict__ W0f,
    const float* __restrict__ W1, __half* __restrict__ W1f,
    const float* __restrict__ W2, __half* __restrict__ W2f) {
    const int b = blockIdx.x;
    const int t = threadIdx.x;
    if (b < 16384) {                     // conv_h: N*16 = 4,194,304 elems
        int i = b * 256 + t;
        h16[i] = __float2half(h[i]);
    } else if (b < 24576) {              // prep_edges: N*8 = 2,097,152 edges
        int e = (b - 16384) * 256 + t;
        int i = e >> 3;
        int n = nbr[e];
        float dx = pos[i * 3 + 0] - pos[n * 3 + 0];
        float dy = pos[i * 3 + 1] - pos[n * 3 + 1];
        float dz = pos[i * 3 + 2] - pos[n * 3 + 2];
        float d = sqrtf(dx * dx + dy * dy + dz * dz);
        if (d == 0.0f) d = 0.5f;         // reference: where(dist==0, 0.5, dist)
        invd[e] = __float2half((1.0f / d) * 0.00390625f);  // prescale 1/256
    } else if (b < 24640) {              // W0 fragment shuffle: KT=128, FO=128
        int e = (b - 24576) * 256 + t;   // 16384 elems
        int j = e & 7;
        int lane = (e >> 3) & 63;
        int rest = e >> 9;
        int tt = rest % 8;
        int s = rest / 8;
        int k = s * 32 + (lane >> 4) * 8 + j;
        int n = tt * 16 + (lane & 15);
        W0f[e] = __float2half(W0[k * 128 + n]);
    } else if (b < 25152) {              // W1 fragment shuffle: KT=1024, FO=128
        int e = (b - 24640) * 256 + t;   // 131072 elems
        int j = e & 7;
        int lane = (e >> 3) & 63;
        int rest = e >> 9;
        int tt = rest % 8;
        int s = rest / 8;
        int k = s * 32 + (lane >> 4) * 8 + j;
        int n = tt * 16 + (lane & 15);
        W1f[e] = __float2half(W1[k * 128 + n]);
    } else {                             // W2 stacked shuffle: 16384 elems
        int e = (b - 25152) * 256 + t;
        int j = e & 7;
        int lane = (e >> 3) & 63;
        int rest = e >> 9;
        int tt = rest % 8;
        int s = rest / 8;
        int k = s * 32 + (lane >> 4) * 8 + j;
        W2f[e] = __float2half(W2[(size_t)(tt * 128 + k) * 16 + (lane & 15)]);
    }
}

// ---------------- L0: F_IN=16, F_OUT=128, 128 rows/block ----------------
__global__ __launch_bounds__(256) void layer0_kernel(
    const __half* __restrict__ hprev, const __half* __restrict__ invd,
    const int* __restrict__ nbr, const __half* __restrict__ Wf,
    const float* __restrict__ bias, __half* __restrict__ outp) {
    __shared__ __align__(16) __half Bs[16384];  // 32 KB: weights, then h1-tile bounce

    const int tid = threadIdx.x;
    const int wave = tid >> 6;
    const int lane = tid & 63;
    const int quad = lane >> 4;
    const int lmod = lane & 15;
    const int mbase = blockIdx.x * 128 + wave * 16 + lmod;

    int idx[2][8];
    f16x8 invr[2];
#pragma unroll
    for (int mt = 0; mt < 2; ++mt) {
        const int m = mbase + mt * 64;
        const int4* nrow = (const int4*)(nbr + (size_t)m * 8);
        const int4 iA = nrow[0];
        const int4 iB = nrow[1];
        idx[mt][0] = iA.x; idx[mt][1] = iA.y; idx[mt][2] = iA.z; idx[mt][3] = iA.w;
        idx[mt][4] = iB.x; idx[mt][5] = iB.y; idx[mt][6] = iB.z; idx[mt][7] = iB.w;
        invr[mt] = *(const f16x8*)(invd + (size_t)m * 8);
    }

    f32x4 acc[2][8];
#pragma unroll
    for (int mt = 0; mt < 2; ++mt)
#pragma unroll
        for (int t = 0; t < 8; ++t) acc[mt][t] = f32x4{0.f, 0.f, 0.f, 0.f};

    {
        const uint4* src = (const uint4*)Wf;
        uint4* dst = (uint4*)Bs;
#pragma unroll
        for (int i = 0; i < 8; ++i) dst[i * 256 + tid] = src[i * 256 + tid];
    }
    __syncthreads();

#pragma unroll
    for (int s = 0; s < 4; ++s) {
        const int nb = 2 * s + (quad >> 1);
        f16x8 as[2];
#pragma unroll
        for (int mt = 0; mt < 2; ++mt) {
            f16x8 av = *(const f16x8*)(hprev + (size_t)idx[mt][nb] * 16 + (quad & 1) * 8);
            as[mt] = av * invr[mt][nb];
        }
#pragma unroll
        for (int t = 0; t < 8; ++t) {
            f16x8 b = *(const f16x8*)(Bs + ((size_t)(s * 8 + t) * 64 + lane) * 8);
#pragma unroll
            for (int mt = 0; mt < 2; ++mt)
                acc[mt][t] = __builtin_amdgcn_mfma_f32_16x16x32_f16(as[mt], b, acc[mt][t], 0, 0, 0);
        }
    }

    // ---- Epilogue: bounce 128x128 f16 tile through Bs, coalesced dump ----
    __syncthreads();  // all Bs (weights) reads complete before overwrite
#pragma unroll
    for (int mt = 0; mt < 2; ++mt) {
#pragma unroll
        for (int t = 0; t < 8; ++t) {
            const int col = t * 16 + lmod;
            const float bv = bias[col];
#pragma unroll
            for (int rr = 0; rr < 4; ++rr) {
                const int lrow = mt * 64 + wave * 16 + quad * 4 + rr;
                float v = acc[mt][t][rr] * 256.0f + bv;
                Bs[lrow * 128 + col] = __float2half(v);
            }
        }
    }
    __syncthreads();
    {
        const int lrow = tid >> 1;                 // 0..127
        const int cb = (tid & 1) * 64;             // col base 0 or 64
        __half* gdst = outp + (size_t)(blockIdx.x * 128 + lrow) * 128 + cb;
        const __half* lsrc = Bs + lrow * 128 + cb;
#pragma unroll
        for (int j = 0; j < 8; ++j)
            *(f16x8*)(gdst + j * 8) = *(const f16x8*)(lsrc + j * 8);
    }
}

// ------- L1+P: F_IN=128, F_OUT=128, 64 rows/block, fused P projection -------
// 512 threads / 8 waves; wave w -> (wm = w>>2: row half, wt = w&3: col pair).
// Wave computes rows [wm*32, wm*32+32) x col-tiles {wt*2, wt*2+1}:
// each A-fragment ds_read feeds TWO MFMAs (the LDS pipe was the binder).
// LDS: seg-major + XOR swizzle, 16B granules: off16(seg,row) =
//   seg*64 + (row & ~15) + ((row ^ seg) & 15)   -> spans [0, 1024) granules.
__device__ __forceinline__ int off16(int seg, int row) {
    return seg * 64 + (row & ~15) + ((row ^ seg) & 15);
}

__global__ __launch_bounds__(512, 4) void layer1p_kernel(
    const __half* __restrict__ hprev, const __half* __restrict__ invd,
    const int* __restrict__ nbr, const __half* __restrict__ Wf,
    const __half* __restrict__ Wf2s, const float* __restrict__ bias,
    __half* __restrict__ Pout) {
    __shared__ __align__(16) __half As[2][8192];  // 2 x 1024 granules x 16B = 32 KB

    const int tid = threadIdx.x;
    const int wave = tid >> 6;
    const int lane = tid & 63;
    const int quad = lane >> 4;
    const int lmod = lane & 15;
    const int rowblk = blockIdx.x * 64;
    const int seg = lmod;               // staging: this thread's 16B segment
    const int wm = wave >> 2;           // row half: rows wm*32 .. wm*32+31
    const int wt = wave & 3;            // col pair: tiles wt*2, wt*2+1

    // Staging rows (unchanged from r19): r0 = wave*4 + quad and r0+32.
    const int r0 = wave * 4 + quad;
    const int* nbp = nbr + (size_t)(rowblk + r0) * 8;      // +256 ints = row r0+32
    const __half* ivp = invd + (size_t)(rowblk + r0) * 8;  // +256 halves = row r0+32

    const int soff0 = off16(seg, r0) * 8;        // halves
    const int soff1 = off16(seg, r0 + 32) * 8;

    // Fragment-read offsets (halves): off16(ks*4+quad, m*16+lmod)*8 =
    // roff4[ks] + m*128, m = wm*2 + mi.
    int roff4[4];
#pragma unroll
    for (int ks = 0; ks < 4; ++ks) {
        const int sg = ks * 4 + quad;
        roff4[ks] = (sg * 64 + ((lmod ^ sg) & 15)) * 8;
    }

    // B fragments for this wave's two col-tiles: frag (s, wt*2+tl) at
    // WfB + (s*8 + tl)*512 halves.
    const __half* WfB = Wf + ((size_t)(wt * 2) * 64 + lane) * 8;

    // Half-width B ring: phase p = nb*2 + h covers s = 2p, 2p+1.
    f16x8 Bc[2][2], Bn[2][2];
#pragma unroll
    for (int ks2 = 0; ks2 < 2; ++ks2)
#pragma unroll
        for (int tl = 0; tl < 2; ++tl)
            Bc[ks2][tl] = *(const f16x8*)(WfB + (size_t)(ks2 * 8 + tl) * 512);

    // 2-deep gather ring (global->VGPR loads cross barriers); indices JIT.
    f16x8 ga[2][2];
    {
        int id0[2], id1[2];
        id0[0] = nbp[0];   id0[1] = nbp[256];
        ga[0][0] = *(const f16x8*)(hprev + (size_t)id0[0] * 128 + seg * 8);
        ga[0][1] = *(const f16x8*)(hprev + (size_t)id0[1] * 128 + seg * 8);
        id1[0] = nbp[1];   id1[1] = nbp[257];
        ga[1][0] = *(const f16x8*)(hprev + (size_t)id1[0] * 128 + seg * 8);
        ga[1][1] = *(const f16x8*)(hprev + (size_t)id1[1] * 128 + seg * 8);
    }

    // Stage neighbor 0 (scaled) into As[0].
    {
        const _Float16 s0 = *(const _Float16*)(ivp + 0);
        const _Float16 s1 = *(const _Float16*)(ivp + 256);
        *(f16x8*)(&As[0][soff0]) = ga[0][0] * s0;
        *(f16x8*)(&As[0][soff1]) = ga[0][1] * s1;
    }
    __syncthreads();

    f32x4 acc[2][2];
#pragma unroll
    for (int mi = 0; mi < 2; ++mi) {
        acc[mi][0] = f32x4{0.f, 0.f, 0.f, 0.f};
        acc[mi][1] = f32x4{0.f, 0.f, 0.f, 0.f};
    }

#pragma unroll
    for (int nb = 0; nb < 8; ++nb) {
        const int cur = nb & 1;
        // JIT indices for neighbor nb+2 (L1-hot), gather into ga[cur]
        // (slot's old data = neighbor nb, already staged).
        if (nb < 6) {
            int idn[2];
            idn[0] = nbp[nb + 2];
            idn[1] = nbp[nb + 258];
            ga[cur][0] = *(const f16x8*)(hprev + (size_t)idn[0] * 128 + seg * 8);
            ga[cur][1] = *(const f16x8*)(hprev + (size_t)idn[1] * 128 + seg * 8);
        }
        // Compute from As[cur]: two B half-phases (ks = h*2 + ks2).
        // Each A-read (mi, ks) feeds BOTH col-tiles.
#pragma unroll
        for (int h = 0; h < 2; ++h) {
            const int p = nb * 2 + h;
            if (p < 15) {
#pragma unroll
                for (int ks2 = 0; ks2 < 2; ++ks2)
#pragma unroll
                    for (int tl = 0; tl < 2; ++tl)
                        Bn[ks2][tl] = *(const f16x8*)(WfB + (size_t)(((p + 1) * 2 + ks2) * 8 + tl) * 512);
            }
#pragma unroll
            for (int mi = 0; mi < 2; ++mi) {
#pragma unroll
                for (int ks2 = 0; ks2 < 2; ++ks2) {
                    f16x8 a = *(const f16x8*)(&As[cur][roff4[h * 2 + ks2] + (wm * 2 + mi) * 128]);
                    acc[mi][0] = __builtin_amdgcn_mfma_f32_16x16x32_f16(a, Bc[ks2][0], acc[mi][0], 0, 0, 0);
                    acc[mi][1] = __builtin_amdgcn_mfma_f32_16x16x32_f16(a, Bc[ks2][1], acc[mi][1], 0, 0, 0);
                }
            }
#pragma unroll
            for (int ks2 = 0; ks2 < 2; ++ks2) {
                Bc[ks2][0] = Bn[ks2][0];
                Bc[ks2][1] = Bn[ks2][1];
            }
        }
        // Stage neighbor nb+1 (scaled), then barrier.
        if (nb < 7) {
            const _Float16 s0 = *(const _Float16*)(ivp + nb + 1);
            const _Float16 s1 = *(const _Float16*)(ivp + nb + 257);
            *(f16x8*)(&As[cur ^ 1][soff0]) = ga[(nb + 1) & 1][0] * s0;
            *(f16x8*)(&As[cur ^ 1][soff1]) = ga[(nb + 1) & 1][1] * s1;
            __syncthreads();
        }
    }

    // ---- Fused epilogue: h2 = leaky(acc*256 + b1) -> LDS (swizzled) ----
    // As[0] is free (last read at nb=6's compute, before the last barrier).
    // h2 element (row,col) at granule off16(col>>3, row), half (col&7).
    // This wave writes rows wm*32 + mi*16 + quad*4 + rr,
    // cols wt*32 + tl*16 + lmod.
    __half* As0 = &As[0][0];
#pragma unroll
    for (int mi = 0; mi < 2; ++mi) {
#pragma unroll
        for (int tl = 0; tl < 2; ++tl) {
            const int col = wt * 32 + tl * 16 + lmod;
            const float bv = bias[col];
            const int sg = col >> 3;
            const int jj = col & 7;
#pragma unroll
            for (int rr = 0; rr < 4; ++rr) {
                const int row = wm * 32 + mi * 16 + quad * 4 + rr;
                float v = acc[mi][tl][rr] * 256.0f + bv;
                v = (v >= 0.f) ? v : 0.01f * v;
                As0[off16(sg, row) * 8 + jj] = __float2half(v);
            }
        }
    }
    __syncthreads();

    // ---- P = h2 @ W2s (K=128, 4 k-steps); same 2x2 mapping ----
    const __half* WfB2 = Wf2s + ((size_t)(wt * 2) * 64 + lane) * 8;
    f16x8 B2[4][2];
#pragma unroll
    for (int ks = 0; ks < 4; ++ks)
#pragma unroll
        for (int tl = 0; tl < 2; ++tl)
            B2[ks][tl] = *(const f16x8*)(WfB2 + (size_t)(ks * 8 + tl) * 512);

    f32x4 acc2[2][2];
#pragma unroll
    for (int mi = 0; mi < 2; ++mi) {
        acc2[mi][0] = f32x4{0.f, 0.f, 0.f, 0.f};
        acc2[mi][1] = f32x4{0.f, 0.f, 0.f, 0.f};
    }
#pragma unroll
    for (int mi = 0; mi < 2; ++mi) {
#pragma unroll
        for (int ks = 0; ks < 4; ++ks) {
            f16x8 a2 = *(const f16x8*)(&As0[roff4[ks] + (wm * 2 + mi) * 128]);
            acc2[mi][0] = __builtin_amdgcn_mfma_f32_16x16x32_f16(a2, B2[ks][0], acc2[mi][0], 0, 0, 0);
            acc2[mi][1] = __builtin_amdgcn_mfma_f32_16x16x32_f16(a2, B2[ks][1], acc2[mi][1], 0, 0, 0);
        }
    }

    // ---- write P (fp16, true scale) ----
#pragma unroll
    for (int mi = 0; mi < 2; ++mi) {
#pragma unroll
        for (int tl = 0; tl < 2; ++tl) {
            const int col = wt * 32 + tl * 16 + lmod;
#pragma unroll
            for (int rr = 0; rr < 4; ++rr) {
                const int grow = rowblk + wm * 32 + mi * 16 + quad * 4 + rr;
                Pout[(size_t)grow * 128 + col] = __float2half(acc2[mi][tl][rr]);
            }
        }
    }
}

// ---- Reduce: out[i][c] = 256*sum_k invd[i,k]*P[nbr[i,k]][k*16+c] + b2[c] ----
// 2-way split per node: thread (d, half) covers cols half*8..+8.
// 8 gathers/thread, 2048 blocks = 32 waves/CU: 2x memory concurrency.
__global__ __launch_bounds__(256) void reduce_kernel(
    const __half* __restrict__ P, const __half* __restrict__ invd,
    const int* __restrict__ nbr, const float* __restrict__ b2,
    float* __restrict__ outp) {
    const int t = blockIdx.x * 256 + threadIdx.x;
    const int d = t >> 1;
    const int half = t & 1;

    const int4* nrow = (const int4*)(nbr + (size_t)d * 8);
    const int4 iA = nrow[0];
    const int4 iB = nrow[1];
    const int idx[8] = {iA.x, iA.y, iA.z, iA.w, iB.x, iB.y, iB.z, iB.w};
    const f16x8 iv = *(const f16x8*)(invd + (size_t)d * 8);

    // Issue all 8 gather loads up front.
    f16x8 v[8];
#pragma unroll
    for (int k = 0; k < 8; ++k)
        v[k] = *(const f16x8*)(P + (size_t)idx[k] * 128 + k * 16 + half * 8);

    float acc[8];
#pragma unroll
    for (int c = 0; c < 8; ++c) acc[c] = 0.f;
#pragma unroll
    for (int k = 0; k < 8; ++k) {
        const float w = (float)iv[k];
#pragma unroll
        for (int c = 0; c < 8; ++c) acc[c] += w * (float)v[k][c];
    }

    const float* bp = b2 + half * 8;
    float4 o[2];
#pragma unroll
    for (int q = 0; q < 2; ++q) {
        o[q].x = acc[q * 4 + 0] * 256.0f + bp[q * 4 + 0];
        o[q].y = acc[q * 4 + 1] * 256.0f + bp[q * 4 + 1];
        o[q].z = acc[q * 4 + 2] * 256.0f + bp[q * 4 + 2];
        o[q].w = acc[q * 4 + 3] * 256.0f + bp[q * 4 + 3];
    }
    float4* dst = (float4*)(outp + (size_t)d * 16 + half * 8);
    dst[0] = o[0];
    dst[1] = o[1];
}

extern "C" void kernel_launch(void* const* d_in, const int* in_sizes, int n_in,
                              void* d_out, int out_size, void* d_ws, size_t ws_size,
                              hipStream_t stream) {
    const float* h   = (const float*)d_in[0];
    const float* pos = (const float*)d_in[1];
    const int*   nbr = (const int*)d_in[2];
    const float* W0  = (const float*)d_in[3];
    const float* b0  = (const float*)d_in[4];
    const float* W1  = (const float*)d_in[5];
    const float* b1  = (const float*)d_in[6];
    const float* W2  = (const float*)d_in[7];
    const float* b2  = (const float*)d_in[8];

    const int N = NNODES;

    // ws: h1 (64 MiB) + P (64 MiB) = 128 MiB exactly.
    char* w = (char*)d_ws;
    __half* h1 = (__half*)w;                               // 67,108,864 B
    __half* P  = (__half*)(w + (size_t)67108864);          // 67,108,864 B
    __half* invd2 = (__half*)w;                            // 4 MiB, into dead h1

    // d_out doubles as scratch until reduce overwrites all of it (16 MiB).
    char* ob = (char*)d_out;
    __half* invd = (__half*)(ob + 0);                      // 4,194,304 B
    __half* h16  = (__half*)(ob + 4194304);                // 8,388,608 B
    __half* W0f  = (__half*)(ob + 12582912);               // 32,768 B
    __half* W1f  = (__half*)(ob + 12615680);               // 262,144 B
    __half* Wf2s = (__half*)(ob + 12877824);               // 32,768 B (end 12,910,592)

    // Fused prep: 16384 + 8192 + 64 + 512 + 64 = 25216 blocks.
    prep_all_kernel<<<25216, 256, 0, stream>>>(h, h16, pos, nbr, invd,
                                               W0, W0f, W1, W1f, W2, Wf2s);

    layer0_kernel<<<N / 128, 256, 0, stream>>>(h16, invd, nbr, W0f, b0, h1);
    layer1p_kernel<<<N / 64, 512, 0, stream>>>(h1, invd, nbr, W1f, Wf2s, b1, P);

    // h1 is dead now; move invd out of d_out before reduce writes d_out.
    (void)hipMemcpyAsync(invd2, invd, 4194304, hipMemcpyDeviceToDevice, stream);

    reduce_kernel<<<(N * 2) / 256, 256, 0, stream>>>(P, invd2, nbr, b2, (float*)d_out);
}

// Round 10
// 315.036 us; speedup vs baseline: 1.0378x; 1.0378x over previous
//
#include <hip/hip_runtime.h>
#include <hip/hip_fp16.h>

// 3-layer gather-GEMM GNN (N=262144, K=8, 16->128->128->16), f16 MFMA.
// Round 22: layer1p reverted EXACTLY to r19 (117us, VGPR 44, spill-free) —
// r20 (deeper gather ring) and r21 (2x A-reuse) both regressed: bytes are
// fixed and dur*BW=const; every inner-loop instruction/state addition slows
// the issue pace. r19 is the balanced optimum for this structure.
// This round pushes the OTHER 196us (layer0+reduce+prep): reduce goes
// 2-way -> 4-way split per node (thread (d,q) covers cols q*4..+4; 8
// gathers of 8B; 4096 blocks = 2x TLP). The 4 threads of a node read
// adjacent 8B of the same 32B P-segment -> same 64B lines, same traffic,
// double concurrency. Per-element k-order unchanged -> bit-identical.
// prep_all / layer0 unchanged from r18/r19.
//
// Workspace: ws = h1 (64 MiB) + P (64 MiB) = 128 MiB exactly. invd/h16/Wf live
// in d_out scratch; invd is d2d-copied into dead h1 before the reduce (which
// writes d_out).

typedef _Float16 f16x8 __attribute__((ext_vector_type(8)));
typedef _Float16 f16x4 __attribute__((ext_vector_type(4)));
typedef float f32x4 __attribute__((ext_vector_type(4)));

#define NNODES 262144

// ---- Fused prep: [0,16384) conv_h | [16384,24576) prep_edges |
//      [24576,24640) shuffle W0 | [24640,25152) shuffle W1 |
//      [25152,25216) shuffle W2s ----
__global__ __launch_bounds__(256) void prep_all_kernel(
    const float* __restrict__ h, __half* __restrict__ h16,
    const float* __restrict__ pos, const int* __restrict__ nbr,
    __half* __restrict__ invd,
    const float* __restrict__ W0, __half* __restrict__ W0f,
    const float* __restrict__ W1, __half* __restrict__ W1f,
    const float* __restrict__ W2, __half* __restrict__ W2f) {
    const int b = blockIdx.x;
    const int t = threadIdx.x;
    if (b < 16384) {                     // conv_h: N*16 = 4,194,304 elems
        int i = b * 256 + t;
        h16[i] = __float2half(h[i]);
    } else if (b < 24576) {              // prep_edges: N*8 = 2,097,152 edges
        int e = (b - 16384) * 256 + t;
        int i = e >> 3;
        int n = nbr[e];
        float dx = pos[i * 3 + 0] - pos[n * 3 + 0];
        float dy = pos[i * 3 + 1] - pos[n * 3 + 1];
        float dz = pos[i * 3 + 2] - pos[n * 3 + 2];
        float d = sqrtf(dx * dx + dy * dy + dz * dz);
        if (d == 0.0f) d = 0.5f;         // reference: where(dist==0, 0.5, dist)
        invd[e] = __float2half((1.0f / d) * 0.00390625f);  // prescale 1/256
    } else if (b < 24640) {              // W0 fragment shuffle: KT=128, FO=128
        int e = (b - 24576) * 256 + t;   // 16384 elems
        int j = e & 7;
        int lane = (e >> 3) & 63;
        int rest = e >> 9;
        int tt = rest % 8;
        int s = rest / 8;
        int k = s * 32 + (lane >> 4) * 8 + j;
        int n = tt * 16 + (lane & 15);
        W0f[e] = __float2half(W0[k * 128 + n]);
    } else if (b < 25152) {              // W1 fragment shuffle: KT=1024, FO=128
        int e = (b - 24640) * 256 + t;   // 131072 elems
        int j = e & 7;
        int lane = (e >> 3) & 63;
        int rest = e >> 9;
        int tt = rest % 8;
        int s = rest / 8;
        int k = s * 32 + (lane >> 4) * 8 + j;
        int n = tt * 16 + (lane & 15);
        W1f[e] = __float2half(W1[k * 128 + n]);
    } else {                             // W2 stacked shuffle: 16384 elems
        int e = (b - 25152) * 256 + t;
        int j = e & 7;
        int lane = (e >> 3) & 63;
        int rest = e >> 9;
        int tt = rest % 8;
        int s = rest / 8;
        int k = s * 32 + (lane >> 4) * 8 + j;
        W2f[e] = __float2half(W2[(size_t)(tt * 128 + k) * 16 + (lane & 15)]);
    }
}

// ---------------- L0: F_IN=16, F_OUT=128, 128 rows/block ----------------
__global__ __launch_bounds__(256) void layer0_kernel(
    const __half* __restrict__ hprev, const __half* __restrict__ invd,
    const int* __restrict__ nbr, const __half* __restrict__ Wf,
    const float* __restrict__ bias, __half* __restrict__ outp) {
    __shared__ __align__(16) __half Bs[16384];  // 32 KB: weights, then h1-tile bounce

    const int tid = threadIdx.x;
    const int wave = tid >> 6;
    const int lane = tid & 63;
    const int quad = lane >> 4;
    const int lmod = lane & 15;
    const int mbase = blockIdx.x * 128 + wave * 16 + lmod;

    int idx[2][8];
    f16x8 invr[2];
#pragma unroll
    for (int mt = 0; mt < 2; ++mt) {
        const int m = mbase + mt * 64;
        const int4* nrow = (const int4*)(nbr + (size_t)m * 8);
        const int4 iA = nrow[0];
        const int4 iB = nrow[1];
        idx[mt][0] = iA.x; idx[mt][1] = iA.y; idx[mt][2] = iA.z; idx[mt][3] = iA.w;
        idx[mt][4] = iB.x; idx[mt][5] = iB.y; idx[mt][6] = iB.z; idx[mt][7] = iB.w;
        invr[mt] = *(const f16x8*)(invd + (size_t)m * 8);
    }

    f32x4 acc[2][8];
#pragma unroll
    for (int mt = 0; mt < 2; ++mt)
#pragma unroll
        for (int t = 0; t < 8; ++t) acc[mt][t] = f32x4{0.f, 0.f, 0.f, 0.f};

    {
        const uint4* src = (const uint4*)Wf;
        uint4* dst = (uint4*)Bs;
#pragma unroll
        for (int i = 0; i < 8; ++i) dst[i * 256 + tid] = src[i * 256 + tid];
    }
    __syncthreads();

#pragma unroll
    for (int s = 0; s < 4; ++s) {
        const int nb = 2 * s + (quad >> 1);
        f16x8 as[2];
#pragma unroll
        for (int mt = 0; mt < 2; ++mt) {
            f16x8 av = *(const f16x8*)(hprev + (size_t)idx[mt][nb] * 16 + (quad & 1) * 8);
            as[mt] = av * invr[mt][nb];
        }
#pragma unroll
        for (int t = 0; t < 8; ++t) {
            f16x8 b = *(const f16x8*)(Bs + ((size_t)(s * 8 + t) * 64 + lane) * 8);
#pragma unroll
            for (int mt = 0; mt < 2; ++mt)
                acc[mt][t] = __builtin_amdgcn_mfma_f32_16x16x32_f16(as[mt], b, acc[mt][t], 0, 0, 0);
        }
    }

    // ---- Epilogue: bounce 128x128 f16 tile through Bs, coalesced dump ----
    __syncthreads();  // all Bs (weights) reads complete before overwrite
#pragma unroll
    for (int mt = 0; mt < 2; ++mt) {
#pragma unroll
        for (int t = 0; t < 8; ++t) {
            const int col = t * 16 + lmod;
            const float bv = bias[col];
#pragma unroll
            for (int rr = 0; rr < 4; ++rr) {
                const int lrow = mt * 64 + wave * 16 + quad * 4 + rr;
                float v = acc[mt][t][rr] * 256.0f + bv;
                Bs[lrow * 128 + col] = __float2half(v);
            }
        }
    }
    __syncthreads();
    {
        const int lrow = tid >> 1;                 // 0..127
        const int cb = (tid & 1) * 64;             // col base 0 or 64
        __half* gdst = outp + (size_t)(blockIdx.x * 128 + lrow) * 128 + cb;
        const __half* lsrc = Bs + lrow * 128 + cb;
#pragma unroll
        for (int j = 0; j < 8; ++j)
            *(f16x8*)(gdst + j * 8) = *(const f16x8*)(lsrc + j * 8);
    }
}

// ------- L1+P: F_IN=128, F_OUT=128, 64 rows/block, fused P projection -------
// 512 threads / 8 waves; wave owns one col-tile t = wave.  (r19 form.)
// LDS: seg-major + XOR swizzle, 16B granules: off16(seg,row) =
//   seg*64 + (row & ~15) + ((row ^ seg) & 15)   -> spans [0, 1024) granules.
__device__ __forceinline__ int off16(int seg, int row) {
    return seg * 64 + (row & ~15) + ((row ^ seg) & 15);
}

__global__ __launch_bounds__(512, 4) void layer1p_kernel(
    const __half* __restrict__ hprev, const __half* __restrict__ invd,
    const int* __restrict__ nbr, const __half* __restrict__ Wf,
    const __half* __restrict__ Wf2s, const float* __restrict__ bias,
    __half* __restrict__ Pout) {
    __shared__ __align__(16) __half As[2][8192];  // 2 x 1024 granules x 16B = 32 KB

    const int tid = threadIdx.x;
    const int wave = tid >> 6;          // 0..7: this wave's col-tile
    const int lane = tid & 63;
    const int quad = lane >> 4;
    const int lmod = lane & 15;
    const int rowblk = blockIdx.x * 64;
    const int seg = lmod;               // staging: this thread's 16B segment

    // Staging rows: r0 = wave*4 + quad (0..31) and r0+32; seg = lmod.
    const int r0 = wave * 4 + quad;
    const int* nbp = nbr + (size_t)(rowblk + r0) * 8;      // +256 ints = row r0+32
    const __half* ivp = invd + (size_t)(rowblk + r0) * 8;  // +256 halves = row r0+32

    const int soff0 = off16(seg, r0) * 8;        // halves
    const int soff1 = off16(seg, r0 + 32) * 8;

    // Fragment-read offsets (halves): off16(ks*4+quad, m*16+lmod)*8 =
    // roff4[ks] + m*128.
    int roff4[4];
#pragma unroll
    for (int ks = 0; ks < 4; ++ks) {
        const int sg = ks * 4 + quad;
        roff4[ks] = (sg * 64 + ((lmod ^ sg) & 15)) * 8;
    }

    // This wave's B fragments: col-tile t = wave; k-step s at +s*4096 halves.
    const __half* WfB = Wf + ((size_t)wave * 64 + lane) * 8;

    // Half-width B ring: phase p = nb*2 + h covers s = 2p, 2p+1.
    f16x8 Bc[2], Bn[2];
#pragma unroll
    for (int ks2 = 0; ks2 < 2; ++ks2)
        Bc[ks2] = *(const f16x8*)(WfB + (size_t)ks2 * 4096);

    // 2-deep gather ring (global->VGPR loads cross barriers); indices JIT.
    f16x8 ga[2][2];
    {
        int id0[2], id1[2];
        id0[0] = nbp[0];   id0[1] = nbp[256];
        ga[0][0] = *(const f16x8*)(hprev + (size_t)id0[0] * 128 + seg * 8);
        ga[0][1] = *(const f16x8*)(hprev + (size_t)id0[1] * 128 + seg * 8);
        id1[0] = nbp[1];   id1[1] = nbp[257];
        ga[1][0] = *(const f16x8*)(hprev + (size_t)id1[0] * 128 + seg * 8);
        ga[1][1] = *(const f16x8*)(hprev + (size_t)id1[1] * 128 + seg * 8);
    }

    // Stage neighbor 0 (scaled) into As[0].
    {
        const _Float16 s0 = *(const _Float16*)(ivp + 0);
        const _Float16 s1 = *(const _Float16*)(ivp + 256);
        *(f16x8*)(&As[0][soff0]) = ga[0][0] * s0;
        *(f16x8*)(&As[0][soff1]) = ga[0][1] * s1;
    }
    __syncthreads();

    f32x4 acc[4];
#pragma unroll
    for (int m = 0; m < 4; ++m) acc[m] = f32x4{0.f, 0.f, 0.f, 0.f};

#pragma unroll
    for (int nb = 0; nb < 8; ++nb) {
        const int cur = nb & 1;
        // JIT indices for neighbor nb+2 (L1-hot), gather into ga[cur]
        // (slot's old data = neighbor nb, already staged).
        if (nb < 6) {
            int idn[2];
            idn[0] = nbp[nb + 2];
            idn[1] = nbp[nb + 258];
            ga[cur][0] = *(const f16x8*)(hprev + (size_t)idn[0] * 128 + seg * 8);
            ga[cur][1] = *(const f16x8*)(hprev + (size_t)idn[1] * 128 + seg * 8);
        }
        // Compute from As[cur]: two B half-phases (ks = h*2 + ks2).
#pragma unroll
        for (int h = 0; h < 2; ++h) {
            const int p = nb * 2 + h;
            if (p < 15) {
#pragma unroll
                for (int ks2 = 0; ks2 < 2; ++ks2)
                    Bn[ks2] = *(const f16x8*)(WfB + (size_t)((p + 1) * 2 + ks2) * 4096);
            }
#pragma unroll
            for (int m = 0; m < 4; ++m) {
#pragma unroll
                for (int ks2 = 0; ks2 < 2; ++ks2) {
                    f16x8 a = *(const f16x8*)(&As[cur][roff4[h * 2 + ks2] + m * 128]);
                    acc[m] = __builtin_amdgcn_mfma_f32_16x16x32_f16(a, Bc[ks2], acc[m], 0, 0, 0);
                }
            }
            Bc[0] = Bn[0];
            Bc[1] = Bn[1];
        }
        // Stage neighbor nb+1 (scaled), then barrier.
        if (nb < 7) {
            const _Float16 s0 = *(const _Float16*)(ivp + nb + 1);
            const _Float16 s1 = *(const _Float16*)(ivp + nb + 257);
            *(f16x8*)(&As[cur ^ 1][soff0]) = ga[(nb + 1) & 1][0] * s0;
            *(f16x8*)(&As[cur ^ 1][soff1]) = ga[(nb + 1) & 1][1] * s1;
            __syncthreads();
        }
    }

    // ---- Fused epilogue: h2 = leaky(acc*256 + b1) -> LDS (swizzled) ----
    // As[0] is free (last read at nb=6's compute, before the last barrier).
    // h2 element (row,col) at granule off16(col>>3, row), half (col&7).
    // Wave writes its 16 cols: col = wave*16 + lmod.
    __half* As0 = &As[0][0];
    {
        const int col = wave * 16 + lmod;
        const float bv = bias[col];
        const int sg = col >> 3;
        const int jj = col & 7;
#pragma unroll
        for (int m = 0; m < 4; ++m) {
#pragma unroll
            for (int rr = 0; rr < 4; ++rr) {
                const int row = m * 16 + quad * 4 + rr;
                float v = acc[m][rr] * 256.0f + bv;
                v = (v >= 0.f) ? v : 0.01f * v;
                As0[off16(sg, row) * 8 + jj] = __float2half(v);
            }
        }
    }
    __syncthreads();

    // ---- P = h2 @ W2s (K=128, 4 k-steps); wave owns col-tile wave ----
    const __half* WfB2 = Wf2s + ((size_t)wave * 64 + lane) * 8;
    f16x8 B2[4];
#pragma unroll
    for (int ks = 0; ks < 4; ++ks)
        B2[ks] = *(const f16x8*)(WfB2 + (size_t)ks * 4096);

    f32x4 acc2[4];
#pragma unroll
    for (int m = 0; m < 4; ++m) acc2[m] = f32x4{0.f, 0.f, 0.f, 0.f};
#pragma unroll
    for (int m = 0; m < 4; ++m) {
#pragma unroll
        for (int ks = 0; ks < 4; ++ks) {
            f16x8 a2 = *(const f16x8*)(&As0[roff4[ks] + m * 128]);
            acc2[m] = __builtin_amdgcn_mfma_f32_16x16x32_f16(a2, B2[ks], acc2[m], 0, 0, 0);
        }
    }

    // ---- write P (fp16, true scale) ----
    {
        const int col = wave * 16 + lmod;
#pragma unroll
        for (int m = 0; m < 4; ++m) {
#pragma unroll
            for (int rr = 0; rr < 4; ++rr) {
                const int grow = rowblk + m * 16 + quad * 4 + rr;
                Pout[(size_t)grow * 128 + col] = __float2half(acc2[m][rr]);
            }
        }
    }
}

// ---- Reduce: out[i][c] = 256*sum_k invd[i,k]*P[nbr[i,k]][k*16+c] + b2[c] ----
// 4-way split per node: thread (d, q) covers cols q*4..q*4+4.
// 8 gathers of 8B/thread, 4096 blocks: 2x the concurrency of the 2-way
// split (r17). Adjacent q-threads read adjacent 8B of the same 32B
// P-segment -> coalesced to the same 64B lines, traffic unchanged.
// Per-element k-order (0..7) unchanged -> bit-identical.
__global__ __launch_bounds__(256) void reduce_kernel(
    const __half* __restrict__ P, const __half* __restrict__ invd,
    const int* __restrict__ nbr, const float* __restrict__ b2,
    float* __restrict__ outp) {
    const int t = blockIdx.x * 256 + threadIdx.x;
    const int d = t >> 2;
    const int q = t & 3;

    const int4* nrow = (const int4*)(nbr + (size_t)d * 8);
    const int4 iA = nrow[0];
    const int4 iB = nrow[1];
    const int idx[8] = {iA.x, iA.y, iA.z, iA.w, iB.x, iB.y, iB.z, iB.w};
    const f16x8 iv = *(const f16x8*)(invd + (size_t)d * 8);

    // Issue all 8 gather loads up front.
    f16x4 v[8];
#pragma unroll
    for (int k = 0; k < 8; ++k)
        v[k] = *(const f16x4*)(P + (size_t)idx[k] * 128 + k * 16 + q * 4);

    float acc[4];
#pragma unroll
    for (int c = 0; c < 4; ++c) acc[c] = 0.f;
#pragma unroll
    for (int k = 0; k < 8; ++k) {
        const float w = (float)iv[k];
#pragma unroll
        for (int c = 0; c < 4; ++c) acc[c] += w * (float)v[k][c];
    }

    const float* bp = b2 + q * 4;
    float4 o;
    o.x = acc[0] * 256.0f + bp[0];
    o.y = acc[1] * 256.0f + bp[1];
    o.z = acc[2] * 256.0f + bp[2];
    o.w = acc[3] * 256.0f + bp[3];
    *(float4*)(outp + (size_t)d * 16 + q * 4) = o;
}

extern "C" void kernel_launch(void* const* d_in, const int* in_sizes, int n_in,
                              void* d_out, int out_size, void* d_ws, size_t ws_size,
                              hipStream_t stream) {
    const float* h   = (const float*)d_in[0];
    const float* pos = (const float*)d_in[1];
    const int*   nbr = (const int*)d_in[2];
    const float* W0  = (const float*)d_in[3];
    const float* b0  = (const float*)d_in[4];
    const float* W1  = (const float*)d_in[5];
    const float* b1  = (const float*)d_in[6];
    const float* W2  = (const float*)d_in[7];
    const float* b2  = (const float*)d_in[8];

    const int N = NNODES;

    // ws: h1 (64 MiB) + P (64 MiB) = 128 MiB exactly.
    char* w = (char*)d_ws;
    __half* h1 = (__half*)w;                               // 67,108,864 B
    __half* P  = (__half*)(w + (size_t)67108864);          // 67,108,864 B
    __half* invd2 = (__half*)w;                            // 4 MiB, into dead h1

    // d_out doubles as scratch until reduce overwrites all of it (16 MiB).
    char* ob = (char*)d_out;
    __half* invd = (__half*)(ob + 0);                      // 4,194,304 B
    __half* h16  = (__half*)(ob + 4194304);                // 8,388,608 B
    __half* W0f  = (__half*)(ob + 12582912);               // 32,768 B
    __half* W1f  = (__half*)(ob + 12615680);               // 262,144 B
    __half* Wf2s = (__half*)(ob + 12877824);               // 32,768 B (end 12,910,592)

    // Fused prep: 16384 + 8192 + 64 + 512 + 64 = 25216 blocks.
    prep_all_kernel<<<25216, 256, 0, stream>>>(h, h16, pos, nbr, invd,
                                               W0, W0f, W1, W1f, W2, Wf2s);

    layer0_kernel<<<N / 128, 256, 0, stream>>>(h16, invd, nbr, W0f, b0, h1);
    layer1p_kernel<<<N / 64, 512, 0, stream>>>(h1, invd, nbr, W1f, Wf2s, b1, P);

    // h1 is dead now; move invd out of d_out before reduce writes d_out.
    (void)hipMemcpyAsync(invd2, invd, 4194304, hipMemcpyDeviceToDevice, stream);

    reduce_kernel<<<(N * 4) / 256, 256, 0, stream>>>(P, invd2, nbr, b2, (float*)d_out);
}

// Round 11
// 313.537 us; speedup vs baseline: 1.0428x; 1.0048x over previous
//
#include <hip/hip_runtime.h>
#include <hip/hip_fp16.h>

// 3-layer gather-GEMM GNN (N=262144, K=8, 16->128->128->16), f16 MFMA.
// Round 23: collapse the prep pipeline into layer0.
//   * conv_h deleted: layer0 gathers h (f32) directly and converts
//     in-register ((_Float16) = same RTN v_cvt_f16_f32 as __float2half ->
//     bit-identical). h16 buffer gone.
//   * prep_edges deleted: layer0 computes invd for its own 128 rows from
//     pos (identical f32 expression -> bit-identical; 4x redundant across
//     quads, same-address gathers L1-broadcast; quad==0 stores rows to
//     global invd for layer1p/reduce).
//   * prep_all shrinks 25216 -> 640 blocks (3 weight shuffles only).
//   * reduce reverted to the r19 2-way split (r22's 4-way was neutral:
//     TLP curve flat, reduce is line-overfetch-bound).
//   * layer1p: r19 exact (118us, VGPR 44, spill-free — frozen optimum).
//
// Workspace: ws = h1 (64 MiB) + P (64 MiB) = 128 MiB exactly. invd/Wf live
// in d_out scratch; invd is d2d-copied into dead h1 before the reduce (which
// writes d_out).

typedef _Float16 f16x8 __attribute__((ext_vector_type(8)));
typedef float f32x4 __attribute__((ext_vector_type(4)));

#define NNODES 262144

// ---- Prep: weight shuffles only.
//      [0,64) W0 | [64,576) W1 | [576,640) W2s ----
__global__ __launch_bounds__(256) void prep_all_kernel(
    const float* __restrict__ W0, __half* __restrict__ W0f,
    const float* __restrict__ W1, __half* __restrict__ W1f,
    const float* __restrict__ W2, __half* __restrict__ W2f) {
    const int b = blockIdx.x;
    const int t = threadIdx.x;
    if (b < 64) {                        // W0 fragment shuffle: KT=128, FO=128
        int e = b * 256 + t;             // 16384 elems
        int j = e & 7;
        int lane = (e >> 3) & 63;
        int rest = e >> 9;
        int tt = rest % 8;
        int s = rest / 8;
        int k = s * 32 + (lane >> 4) * 8 + j;
        int n = tt * 16 + (lane & 15);
        W0f[e] = __float2half(W0[k * 128 + n]);
    } else if (b < 576) {                // W1 fragment shuffle: KT=1024, FO=128
        int e = (b - 64) * 256 + t;      // 131072 elems
        int j = e & 7;
        int lane = (e >> 3) & 63;
        int rest = e >> 9;
        int tt = rest % 8;
        int s = rest / 8;
        int k = s * 32 + (lane >> 4) * 8 + j;
        int n = tt * 16 + (lane & 15);
        W1f[e] = __float2half(W1[k * 128 + n]);
    } else {                             // W2 stacked shuffle: 16384 elems
        int e = (b - 576) * 256 + t;
        int j = e & 7;
        int lane = (e >> 3) & 63;
        int rest = e >> 9;
        int tt = rest % 8;
        int s = rest / 8;
        int k = s * 32 + (lane >> 4) * 8 + j;
        W2f[e] = __float2half(W2[(size_t)(tt * 128 + k) * 16 + (lane & 15)]);
    }
}

// ---------------- L0: F_IN=16, F_OUT=128, 128 rows/block ----------------
// Fuses: h f32->f16 conversion (in-register) + invd computation (from pos,
// stored to global for layer1p/reduce).
__global__ __launch_bounds__(256) void layer0_kernel(
    const float* __restrict__ h, const float* __restrict__ pos,
    const int* __restrict__ nbr, const __half* __restrict__ Wf,
    const float* __restrict__ bias, __half* __restrict__ invd,
    __half* __restrict__ outp) {
    __shared__ __align__(16) __half Bs[16384];  // 32 KB: weights, then h1-tile bounce

    const int tid = threadIdx.x;
    const int wave = tid >> 6;
    const int lane = tid & 63;
    const int quad = lane >> 4;
    const int lmod = lane & 15;
    const int mbase = blockIdx.x * 128 + wave * 16 + lmod;

    // Stage weights (independent of the gather chains below).
    {
        const uint4* src = (const uint4*)Wf;
        uint4* dst = (uint4*)Bs;
#pragma unroll
        for (int i = 0; i < 8; ++i) dst[i * 256 + tid] = src[i * 256 + tid];
    }

    int idx[2][8];
#pragma unroll
    for (int mt = 0; mt < 2; ++mt) {
        const int m = mbase + mt * 64;
        const int4* nrow = (const int4*)(nbr + (size_t)m * 8);
        const int4 iA = nrow[0];
        const int4 iB = nrow[1];
        idx[mt][0] = iA.x; idx[mt][1] = iA.y; idx[mt][2] = iA.z; idx[mt][3] = iA.w;
        idx[mt][4] = iB.x; idx[mt][5] = iB.y; idx[mt][6] = iB.z; idx[mt][7] = iB.w;
    }

    // invd in-kernel (fused prep_edges): identical f32 math as the old
    // prep pass -> bit-identical. 4x redundant across quads (L1-broadcast).
    f16x8 invr[2];
#pragma unroll
    for (int mt = 0; mt < 2; ++mt) {
        const int m = mbase + mt * 64;
        const float px = pos[m * 3 + 0];
        const float py = pos[m * 3 + 1];
        const float pz = pos[m * 3 + 2];
#pragma unroll
        for (int k = 0; k < 8; ++k) {
            const int n = idx[mt][k];
            const float dx = px - pos[n * 3 + 0];
            const float dy = py - pos[n * 3 + 1];
            const float dz = pz - pos[n * 3 + 2];
            float d = sqrtf(dx * dx + dy * dy + dz * dz);
            if (d == 0.0f) d = 0.5f;     // reference: where(dist==0, 0.5, dist)
            invr[mt][k] = (_Float16)((1.0f / d) * 0.00390625f);  // prescale 1/256
        }
        if (quad == 0) *(f16x8*)(invd + (size_t)m * 8) = invr[mt];
    }

    f32x4 acc[2][8];
#pragma unroll
    for (int mt = 0; mt < 2; ++mt)
#pragma unroll
        for (int t = 0; t < 8; ++t) acc[mt][t] = f32x4{0.f, 0.f, 0.f, 0.f};

    __syncthreads();

#pragma unroll
    for (int s = 0; s < 4; ++s) {
        const int nb = 2 * s + (quad >> 1);
        f16x8 as[2];
#pragma unroll
        for (int mt = 0; mt < 2; ++mt) {
            const float* hp = h + (size_t)idx[mt][nb] * 16 + (quad & 1) * 8;
            const float4 f0 = *(const float4*)(hp);
            const float4 f1 = *(const float4*)(hp + 4);
            f16x8 av;
            av[0] = (_Float16)f0.x; av[1] = (_Float16)f0.y;
            av[2] = (_Float16)f0.z; av[3] = (_Float16)f0.w;
            av[4] = (_Float16)f1.x; av[5] = (_Float16)f1.y;
            av[6] = (_Float16)f1.z; av[7] = (_Float16)f1.w;
            as[mt] = av * invr[mt][nb];
        }
#pragma unroll
        for (int t = 0; t < 8; ++t) {
            f16x8 b = *(const f16x8*)(Bs + ((size_t)(s * 8 + t) * 64 + lane) * 8);
#pragma unroll
            for (int mt = 0; mt < 2; ++mt)
                acc[mt][t] = __builtin_amdgcn_mfma_f32_16x16x32_f16(as[mt], b, acc[mt][t], 0, 0, 0);
        }
    }

    // ---- Epilogue: bounce 128x128 f16 tile through Bs, coalesced dump ----
    __syncthreads();  // all Bs (weights) reads complete before overwrite
#pragma unroll
    for (int mt = 0; mt < 2; ++mt) {
#pragma unroll
        for (int t = 0; t < 8; ++t) {
            const int col = t * 16 + lmod;
            const float bv = bias[col];
#pragma unroll
            for (int rr = 0; rr < 4; ++rr) {
                const int lrow = mt * 64 + wave * 16 + quad * 4 + rr;
                float v = acc[mt][t][rr] * 256.0f + bv;
                Bs[lrow * 128 + col] = __float2half(v);
            }
        }
    }
    __syncthreads();
    {
        const int lrow = tid >> 1;                 // 0..127
        const int cb = (tid & 1) * 64;             // col base 0 or 64
        __half* gdst = outp + (size_t)(blockIdx.x * 128 + lrow) * 128 + cb;
        const __half* lsrc = Bs + lrow * 128 + cb;
#pragma unroll
        for (int j = 0; j < 8; ++j)
            *(f16x8*)(gdst + j * 8) = *(const f16x8*)(lsrc + j * 8);
    }
}

// ------- L1+P: F_IN=128, F_OUT=128, 64 rows/block, fused P projection -------
// 512 threads / 8 waves; wave owns one col-tile t = wave.  (r19 form.)
// LDS: seg-major + XOR swizzle, 16B granules: off16(seg,row) =
//   seg*64 + (row & ~15) + ((row ^ seg) & 15)   -> spans [0, 1024) granules.
__device__ __forceinline__ int off16(int seg, int row) {
    return seg * 64 + (row & ~15) + ((row ^ seg) & 15);
}

__global__ __launch_bounds__(512, 4) void layer1p_kernel(
    const __half* __restrict__ hprev, const __half* __restrict__ invd,
    const int* __restrict__ nbr, const __half* __restrict__ Wf,
    const __half* __restrict__ Wf2s, const float* __restrict__ bias,
    __half* __restrict__ Pout) {
    __shared__ __align__(16) __half As[2][8192];  // 2 x 1024 granules x 16B = 32 KB

    const int tid = threadIdx.x;
    const int wave = tid >> 6;          // 0..7: this wave's col-tile
    const int lane = tid & 63;
    const int quad = lane >> 4;
    const int lmod = lane & 15;
    const int rowblk = blockIdx.x * 64;
    const int seg = lmod;               // staging: this thread's 16B segment

    // Staging rows: r0 = wave*4 + quad (0..31) and r0+32; seg = lmod.
    const int r0 = wave * 4 + quad;
    const int* nbp = nbr + (size_t)(rowblk + r0) * 8;      // +256 ints = row r0+32
    const __half* ivp = invd + (size_t)(rowblk + r0) * 8;  // +256 halves = row r0+32

    const int soff0 = off16(seg, r0) * 8;        // halves
    const int soff1 = off16(seg, r0 + 32) * 8;

    // Fragment-read offsets (halves): off16(ks*4+quad, m*16+lmod)*8 =
    // roff4[ks] + m*128.
    int roff4[4];
#pragma unroll
    for (int ks = 0; ks < 4; ++ks) {
        const int sg = ks * 4 + quad;
        roff4[ks] = (sg * 64 + ((lmod ^ sg) & 15)) * 8;
    }

    // This wave's B fragments: col-tile t = wave; k-step s at +s*4096 halves.
    const __half* WfB = Wf + ((size_t)wave * 64 + lane) * 8;

    // Half-width B ring: phase p = nb*2 + h covers s = 2p, 2p+1.
    f16x8 Bc[2], Bn[2];
#pragma unroll
    for (int ks2 = 0; ks2 < 2; ++ks2)
        Bc[ks2] = *(const f16x8*)(WfB + (size_t)ks2 * 4096);

    // 2-deep gather ring (global->VGPR loads cross barriers); indices JIT.
    f16x8 ga[2][2];
    {
        int id0[2], id1[2];
        id0[0] = nbp[0];   id0[1] = nbp[256];
        ga[0][0] = *(const f16x8*)(hprev + (size_t)id0[0] * 128 + seg * 8);
        ga[0][1] = *(const f16x8*)(hprev + (size_t)id0[1] * 128 + seg * 8);
        id1[0] = nbp[1];   id1[1] = nbp[257];
        ga[1][0] = *(const f16x8*)(hprev + (size_t)id1[0] * 128 + seg * 8);
        ga[1][1] = *(const f16x8*)(hprev + (size_t)id1[1] * 128 + seg * 8);
    }

    // Stage neighbor 0 (scaled) into As[0].
    {
        const _Float16 s0 = *(const _Float16*)(ivp + 0);
        const _Float16 s1 = *(const _Float16*)(ivp + 256);
        *(f16x8*)(&As[0][soff0]) = ga[0][0] * s0;
        *(f16x8*)(&As[0][soff1]) = ga[0][1] * s1;
    }
    __syncthreads();

    f32x4 acc[4];
#pragma unroll
    for (int m = 0; m < 4; ++m) acc[m] = f32x4{0.f, 0.f, 0.f, 0.f};

#pragma unroll
    for (int nb = 0; nb < 8; ++nb) {
        const int cur = nb & 1;
        // JIT indices for neighbor nb+2 (L1-hot), gather into ga[cur]
        // (slot's old data = neighbor nb, already staged).
        if (nb < 6) {
            int idn[2];
            idn[0] = nbp[nb + 2];
            idn[1] = nbp[nb + 258];
            ga[cur][0] = *(const f16x8*)(hprev + (size_t)idn[0] * 128 + seg * 8);
            ga[cur][1] = *(const f16x8*)(hprev + (size_t)idn[1] * 128 + seg * 8);
        }
        // Compute from As[cur]: two B half-phases (ks = h*2 + ks2).
#pragma unroll
        for (int h = 0; h < 2; ++h) {
            const int p = nb * 2 + h;
            if (p < 15) {
#pragma unroll
                for (int ks2 = 0; ks2 < 2; ++ks2)
                    Bn[ks2] = *(const f16x8*)(WfB + (size_t)((p + 1) * 2 + ks2) * 4096);
            }
#pragma unroll
            for (int m = 0; m < 4; ++m) {
#pragma unroll
                for (int ks2 = 0; ks2 < 2; ++ks2) {
                    f16x8 a = *(const f16x8*)(&As[cur][roff4[h * 2 + ks2] + m * 128]);
                    acc[m] = __builtin_amdgcn_mfma_f32_16x16x32_f16(a, Bc[ks2], acc[m], 0, 0, 0);
                }
            }
            Bc[0] = Bn[0];
            Bc[1] = Bn[1];
        }
        // Stage neighbor nb+1 (scaled), then barrier.
        if (nb < 7) {
            const _Float16 s0 = *(const _Float16*)(ivp + nb + 1);
            const _Float16 s1 = *(const _Float16*)(ivp + nb + 257);
            *(f16x8*)(&As[cur ^ 1][soff0]) = ga[(nb + 1) & 1][0] * s0;
            *(f16x8*)(&As[cur ^ 1][soff1]) = ga[(nb + 1) & 1][1] * s1;
            __syncthreads();
        }
    }

    // ---- Fused epilogue: h2 = leaky(acc*256 + b1) -> LDS (swizzled) ----
    // As[0] is free (last read at nb=6's compute, before the last barrier).
    // h2 element (row,col) at granule off16(col>>3, row), half (col&7).
    // Wave writes its 16 cols: col = wave*16 + lmod.
    __half* As0 = &As[0][0];
    {
        const int col = wave * 16 + lmod;
        const float bv = bias[col];
        const int sg = col >> 3;
        const int jj = col & 7;
#pragma unroll
        for (int m = 0; m < 4; ++m) {
#pragma unroll
            for (int rr = 0; rr < 4; ++rr) {
                const int row = m * 16 + quad * 4 + rr;
                float v = acc[m][rr] * 256.0f + bv;
                v = (v >= 0.f) ? v : 0.01f * v;
                As0[off16(sg, row) * 8 + jj] = __float2half(v);
            }
        }
    }
    __syncthreads();

    // ---- P = h2 @ W2s (K=128, 4 k-steps); wave owns col-tile wave ----
    const __half* WfB2 = Wf2s + ((size_t)wave * 64 + lane) * 8;
    f16x8 B2[4];
#pragma unroll
    for (int ks = 0; ks < 4; ++ks)
        B2[ks] = *(const f16x8*)(WfB2 + (size_t)ks * 4096);

    f32x4 acc2[4];
#pragma unroll
    for (int m = 0; m < 4; ++m) acc2[m] = f32x4{0.f, 0.f, 0.f, 0.f};
#pragma unroll
    for (int m = 0; m < 4; ++m) {
#pragma unroll
        for (int ks = 0; ks < 4; ++ks) {
            f16x8 a2 = *(const f16x8*)(&As0[roff4[ks] + m * 128]);
            acc2[m] = __builtin_amdgcn_mfma_f32_16x16x32_f16(a2, B2[ks], acc2[m], 0, 0, 0);
        }
    }

    // ---- write P (fp16, true scale) ----
    {
        const int col = wave * 16 + lmod;
#pragma unroll
        for (int m = 0; m < 4; ++m) {
#pragma unroll
            for (int rr = 0; rr < 4; ++rr) {
                const int grow = rowblk + m * 16 + quad * 4 + rr;
                Pout[(size_t)grow * 128 + col] = __float2half(acc2[m][rr]);
            }
        }
    }
}

// ---- Reduce: out[i][c] = 256*sum_k invd[i,k]*P[nbr[i,k]][k*16+c] + b2[c] ----
// 2-way split per node: thread (d, half) covers cols half*8..+8.  (r19 form;
// r22's 4-way was neutral -> TLP-saturated, line-overfetch-bound.)
__global__ __launch_bounds__(256) void reduce_kernel(
    const __half* __restrict__ P, const __half* __restrict__ invd,
    const int* __restrict__ nbr, const float* __restrict__ b2,
    float* __restrict__ outp) {
    const int t = blockIdx.x * 256 + threadIdx.x;
    const int d = t >> 1;
    const int half = t & 1;

    const int4* nrow = (const int4*)(nbr + (size_t)d * 8);
    const int4 iA = nrow[0];
    const int4 iB = nrow[1];
    const int idx[8] = {iA.x, iA.y, iA.z, iA.w, iB.x, iB.y, iB.z, iB.w};
    const f16x8 iv = *(const f16x8*)(invd + (size_t)d * 8);

    // Issue all 8 gather loads up front.
    f16x8 v[8];
#pragma unroll
    for (int k = 0; k < 8; ++k)
        v[k] = *(const f16x8*)(P + (size_t)idx[k] * 128 + k * 16 + half * 8);

    float acc[8];
#pragma unroll
    for (int c = 0; c < 8; ++c) acc[c] = 0.f;
#pragma unroll
    for (int k = 0; k < 8; ++k) {
        const float w = (float)iv[k];
#pragma unroll
        for (int c = 0; c < 8; ++c) acc[c] += w * (float)v[k][c];
    }

    const float* bp = b2 + half * 8;
    float4 o[2];
#pragma unroll
    for (int q = 0; q < 2; ++q) {
        o[q].x = acc[q * 4 + 0] * 256.0f + bp[q * 4 + 0];
        o[q].y = acc[q * 4 + 1] * 256.0f + bp[q * 4 + 1];
        o[q].z = acc[q * 4 + 2] * 256.0f + bp[q * 4 + 2];
        o[q].w = acc[q * 4 + 3] * 256.0f + bp[q * 4 + 3];
    }
    float4* dst = (float4*)(outp + (size_t)d * 16 + half * 8);
    dst[0] = o[0];
    dst[1] = o[1];
}

extern "C" void kernel_launch(void* const* d_in, const int* in_sizes, int n_in,
                              void* d_out, int out_size, void* d_ws, size_t ws_size,
                              hipStream_t stream) {
    const float* h   = (const float*)d_in[0];
    const float* pos = (const float*)d_in[1];
    const int*   nbr = (const int*)d_in[2];
    const float* W0  = (const float*)d_in[3];
    const float* b0  = (const float*)d_in[4];
    const float* W1  = (const float*)d_in[5];
    const float* b1  = (const float*)d_in[6];
    const float* W2  = (const float*)d_in[7];
    const float* b2  = (const float*)d_in[8];

    const int N = NNODES;

    // ws: h1 (64 MiB) + P (64 MiB) = 128 MiB exactly.
    char* w = (char*)d_ws;
    __half* h1 = (__half*)w;                               // 67,108,864 B
    __half* P  = (__half*)(w + (size_t)67108864);          // 67,108,864 B
    __half* invd2 = (__half*)w;                            // 4 MiB, into dead h1

    // d_out doubles as scratch until reduce overwrites all of it (16 MiB).
    char* ob = (char*)d_out;
    __half* invd = (__half*)(ob + 0);                      // 4,194,304 B
    __half* W0f  = (__half*)(ob + 4194304);                // 32,768 B
    __half* W1f  = (__half*)(ob + 4227072);                // 262,144 B
    __half* Wf2s = (__half*)(ob + 4489216);                // 32,768 B (end 4,521,984)

    // Prep: weight shuffles only (64 + 512 + 64 = 640 blocks).
    prep_all_kernel<<<640, 256, 0, stream>>>(W0, W0f, W1, W1f, W2, Wf2s);

    // layer0 fuses h-conversion + invd computation (writes invd).
    layer0_kernel<<<N / 128, 256, 0, stream>>>(h, pos, nbr, W0f, b0, invd, h1);
    layer1p_kernel<<<N / 64, 512, 0, stream>>>(h1, invd, nbr, W1f, Wf2s, b1, P);

    // h1 is dead now; move invd out of d_out before reduce writes d_out.
    (void)hipMemcpyAsync(invd2, invd, 4194304, hipMemcpyDeviceToDevice, stream);

    reduce_kernel<<<(N * 2) / 256, 256, 0, stream>>>(P, invd2, nbr, b2, (float*)d_out);
}